// Round 14
// baseline (29.550 us; speedup 1.0000x reference)
//
#include <hip/hip_runtime.h>

// Problem constants (match reference)
#define BATCH 4
#define QLEN 2048
#define CLEN 2048
#define DIM 512
#define NBLK1 2048          // stream kernels: 8 blocks/CU (full occupancy)
#define CPB 512             // chunks per batch (NBLK1 / BATCH), 4 rows each
#define RPC 4               // rows per chunk

// The reference collapses: einsum 'bqkh,bvha->bqha' has independent k and v,
// and softmax over k sums to exactly 1, so
//   out[b,q,:] = ((sum_cl context[b,cl,:]) @ Wkv[:,D:2D]) @ Wout   for every q.
// query, Wq, mask are dead inputs.
//
// Base = R12 (best: 24.96us). Single change this round: stream kernels at
// 2048 blocks (8/CU) with half-size chunks for finer ramp/drain granularity.
// NT loads/stores on the streams (R12's proven -1.75us). Middle kernels and
// all access patterns byte-identical to R12. In-kernel sync dead (R3/4/7/11).

typedef float f32x4 __attribute__((ext_vector_type(4)));

// ---- K1: partial[blk][d] = sum of its 4 context rows (16.8 MB NT read) ----
__global__ __launch_bounds__(256) void k1_partial(const float* __restrict__ ctx,
                                                  f32x4* __restrict__ partial) {
    __shared__ f32x4 red[256];
    const int blk = blockIdx.x, t = threadIdx.x;
    const int b = blk >> 9, ch = blk & 511;
    const int rg = t >> 7, f4 = t & 127;
    const f32x4* src = reinterpret_cast<const f32x4*>(ctx)
                     + (size_t)(b * CLEN + ch * RPC) * (DIM / 4);
    f32x4 s = {0.f, 0.f, 0.f, 0.f};
#pragma unroll
    for (int i = 0; i < 2; ++i)                    // rows rg, rg+2
        s += __builtin_nontemporal_load(&src[(size_t)(rg + 2 * i) * (DIM / 4) + f4]);
    red[t] = s;
    __syncthreads();
    if (t < 128) {
        f32x4 v = red[t] + red[t + 128];
        partial[(size_t)blk * (DIM / 4) + t] = v;
    }
}

// ---- K2: csum[b][col4] = sum over 512 chunk partials. 512 blocks,
// 2 loads/thread + LDS tree (R12 pattern, adapted). ----
__global__ __launch_bounds__(256) void k2_reduce(const f32x4* __restrict__ partial,
                                                 f32x4* __restrict__ csum) {
    __shared__ f32x4 red[256];
    const int blk = blockIdx.x, t = threadIdx.x;
    const int b = blk >> 7, f4g = blk & 127;
    red[t] = partial[(size_t)(b * CPB + t) * (DIM / 4) + f4g]
           + partial[(size_t)(b * CPB + 256 + t) * (DIM / 4) + f4g];
    __syncthreads();
#pragma unroll
    for (int s = 128; s > 0; s >>= 1) {
        if (t < s) red[t] += red[t + s];
        __syncthreads();
    }
    if (t == 0) csum[b * (DIM / 4) + f4g] = red[0];
}

// ---- K3: vsum[b][e] = sum_d csum[b][d] * Wkv[d][DIM+e]. 128 blocks. ----
__global__ __launch_bounds__(256) void k3_vsum(const float* __restrict__ csum,
                                               const float* __restrict__ Wkv,
                                               float* __restrict__ vsum) {
    __shared__ float cs[DIM];
    __shared__ float red[256];
    const int blk = blockIdx.x, t = threadIdx.x;
    const int b = blk >> 5, eg = blk & 31;
    for (int j = t; j < DIM; j += 256) cs[j] = csum[b * DIM + j];
    __syncthreads();
    const int el = t & 15, dg = t >> 4;
    const int e = eg * 16 + el;
    const float* w = Wkv + (size_t)dg * (2 * DIM) + DIM + e;   // d = i*16 + dg
    float s = 0.f;
#pragma unroll
    for (int i = 0; i < 32; ++i)
        s += cs[i * 16 + dg] * w[(size_t)i * 16 * (2 * DIM)];
    red[t] = s;
    __syncthreads();
#pragma unroll
    for (int st = 128; st >= 16; st >>= 1) {
        if (t < st) red[t] += red[t + st];
        __syncthreads();
    }
    if (t < 16) vsum[b * DIM + eg * 16 + t] = red[t];
}

// ---- K4: orow[b][f] = sum_e vsum[b][e] * Wout[e][f]. Same structure. ----
__global__ __launch_bounds__(256) void k4_orow(const float* __restrict__ vsum,
                                               const float* __restrict__ Wout,
                                               float* __restrict__ orow) {
    __shared__ float vs[DIM];
    __shared__ float red[256];
    const int blk = blockIdx.x, t = threadIdx.x;
    const int b = blk >> 5, fg = blk & 31;
    for (int j = t; j < DIM; j += 256) vs[j] = vsum[b * DIM + j];
    __syncthreads();
    const int fl = t & 15, eg2 = t >> 4;
    const int f = fg * 16 + fl;
    const float* w = Wout + (size_t)eg2 * DIM + f;             // e = i*16 + eg2
    float s = 0.f;
#pragma unroll
    for (int i = 0; i < 32; ++i)
        s += vs[i * 16 + eg2] * w[(size_t)i * 16 * DIM];
    red[t] = s;
    __syncthreads();
#pragma unroll
    for (int st = 128; st >= 16; st >>= 1) {
        if (t < st) red[t] += red[t + st];
        __syncthreads();
    }
    if (t < 16) orow[b * DIM + fg * 16 + t] = red[t];
}

// ---- K5: out[b,q,:] = orow[b,:] for all q (16.8 MB NT write) ----
__global__ __launch_bounds__(256) void k5_bcast(const f32x4* __restrict__ orow4,
                                                f32x4* __restrict__ out) {
    const int blk = blockIdx.x, t = threadIdx.x;
    const int b = blk >> 9, qg = blk & 511;
    const int rg = t >> 7, f4 = t & 127;
    const f32x4 val = orow4[b * (DIM / 4) + f4];               // L2-hot
    f32x4* dst = out + (size_t)(b * QLEN + qg * RPC) * (DIM / 4);
#pragma unroll
    for (int i = 0; i < 2; ++i)                    // rows rg, rg+2
        __builtin_nontemporal_store(val, &dst[(size_t)(rg + 2 * i) * (DIM / 4) + f4]);
}

extern "C" void kernel_launch(void* const* d_in, const int* in_sizes, int n_in,
                              void* d_out, int out_size, void* d_ws, size_t ws_size,
                              hipStream_t stream) {
    // inputs: 0=query (unused), 1=context, 2=mask (unused), 3=Wq (unused), 4=Wkv, 5=Wout
    const float* ctx  = (const float*)d_in[1];
    const float* Wkv  = (const float*)d_in[4];
    const float* Wout = (const float*)d_in[5];
    float* ws = (float*)d_ws;
    float* partial = ws;                                   // NBLK1*DIM = 4 MB
    float* csum    = partial + (size_t)NBLK1 * DIM;        // BATCH*DIM
    float* vsum    = csum + BATCH * DIM;                   // BATCH*DIM
    float* orow    = vsum + BATCH * DIM;                   // BATCH*DIM
    // no memset: every ws word is written before it is read

    k1_partial<<<NBLK1, 256, 0, stream>>>(ctx, (f32x4*)partial);
    k2_reduce<<<512, 256, 0, stream>>>((const f32x4*)partial, (f32x4*)csum);
    k3_vsum<<<128, 256, 0, stream>>>(csum, Wkv, vsum);
    k4_orow<<<128, 256, 0, stream>>>(vsum, Wout, orow);
    k5_bcast<<<NBLK1, 256, 0, stream>>>((const f32x4*)orow, (f32x4*)d_out);
}

// Round 15
// 24.916 us; speedup vs baseline: 1.1860x; 1.1860x over previous
//
#include <hip/hip_runtime.h>

// Problem constants (match reference)
#define BATCH 4
#define QLEN 2048
#define CLEN 2048
#define DIM 512
#define NBLK1 1024          // stream kernels: 4 blocks/CU (measured optimum)
#define CPB 256             // chunks per batch (NBLK1 / BATCH)
#define RPC 8               // rows per chunk

// The reference collapses: einsum 'bqkh,bvha->bqha' has independent k and v,
// and softmax over k sums to exactly 1, so
//   out[b,q,:] = ((sum_cl context[b,cl,:]) @ Wkv[:,D:2D]) @ Wout   for every q.
// query, Wq, mask are dead inputs.
//
// This is the measured optimum over 14 structural variants (R12: 24.96us).
// Key measured facts: NT streams -1.75us; 1024-block streams beat 512/2048;
// kernel-count 2..5 is ~free; all in-kernel grid-sync flavors 10-50x worse
// than kernel boundaries (coop 313us, fence 258us, atomics 37-44us).

typedef float f32x4 __attribute__((ext_vector_type(4)));

// ---- K1: partial[blk][d] = sum of its 8 context rows (16.8 MB NT read) ----
__global__ __launch_bounds__(256) void k1_partial(const float* __restrict__ ctx,
                                                  float4* __restrict__ partial) {
    __shared__ f32x4 red[256];
    const int blk = blockIdx.x, t = threadIdx.x;
    const int b = blk >> 8, ch = blk & 255;
    const int rg = t >> 7, f4 = t & 127;
    const f32x4* src = reinterpret_cast<const f32x4*>(ctx)
                     + (size_t)(b * CLEN + ch * RPC) * (DIM / 4);
    f32x4 s = {0.f, 0.f, 0.f, 0.f};
#pragma unroll
    for (int i = 0; i < 4; ++i)                    // 4 independent NT loads
        s += __builtin_nontemporal_load(&src[(size_t)(rg + 2 * i) * (DIM / 4) + f4]);
    red[t] = s;
    __syncthreads();
    if (t < 128) {
        f32x4 v = red[t] + red[t + 128];
        reinterpret_cast<f32x4*>(partial)[(size_t)blk * (DIM / 4) + t] = v;
    }
}

// ---- K2: csum[b][col4] = sum over 256 chunk partials. 512 blocks. ----
__global__ __launch_bounds__(256) void k2_reduce(const float4* __restrict__ partial,
                                                 float4* __restrict__ csum) {
    __shared__ f32x4 red[256];
    const int blk = blockIdx.x, t = threadIdx.x;
    const int b = blk >> 7, f4g = blk & 127;
    red[t] = reinterpret_cast<const f32x4*>(partial)[(size_t)(b * CPB + t) * (DIM / 4) + f4g];
    __syncthreads();
#pragma unroll
    for (int s = 128; s > 0; s >>= 1) {
        if (t < s) red[t] += red[t + s];
        __syncthreads();
    }
    if (t == 0) reinterpret_cast<f32x4*>(csum)[b * (DIM / 4) + f4g] = red[0];
}

// ---- K3: vsum[b][e] = sum_d csum[b][d] * Wkv[d][DIM+e]. 128 blocks. ----
__global__ __launch_bounds__(256) void k3_vsum(const float* __restrict__ csum,
                                               const float* __restrict__ Wkv,
                                               float* __restrict__ vsum) {
    __shared__ float cs[DIM];
    __shared__ float red[256];
    const int blk = blockIdx.x, t = threadIdx.x;
    const int b = blk >> 5, eg = blk & 31;
    for (int j = t; j < DIM; j += 256) cs[j] = csum[b * DIM + j];
    __syncthreads();
    const int el = t & 15, dg = t >> 4;
    const int e = eg * 16 + el;
    const float* w = Wkv + (size_t)dg * (2 * DIM) + DIM + e;   // d = i*16 + dg
    float s = 0.f;
#pragma unroll
    for (int i = 0; i < 32; ++i)
        s += cs[i * 16 + dg] * w[(size_t)i * 16 * (2 * DIM)];
    red[t] = s;
    __syncthreads();
#pragma unroll
    for (int st = 128; st >= 16; st >>= 1) {
        if (t < st) red[t] += red[t + st];
        __syncthreads();
    }
    if (t < 16) vsum[b * DIM + eg * 16 + t] = red[t];
}

// ---- K4: orow[b][f] = sum_e vsum[b][e] * Wout[e][f]. Same structure. ----
__global__ __launch_bounds__(256) void k4_orow(const float* __restrict__ vsum,
                                               const float* __restrict__ Wout,
                                               float* __restrict__ orow) {
    __shared__ float vs[DIM];
    __shared__ float red[256];
    const int blk = blockIdx.x, t = threadIdx.x;
    const int b = blk >> 5, fg = blk & 31;
    for (int j = t; j < DIM; j += 256) vs[j] = vsum[b * DIM + j];
    __syncthreads();
    const int fl = t & 15, eg2 = t >> 4;
    const int f = fg * 16 + fl;
    const float* w = Wout + (size_t)eg2 * DIM + f;             // e = i*16 + eg2
    float s = 0.f;
#pragma unroll
    for (int i = 0; i < 32; ++i)
        s += vs[i * 16 + eg2] * w[(size_t)i * 16 * DIM];
    red[t] = s;
    __syncthreads();
#pragma unroll
    for (int st = 128; st >= 16; st >>= 1) {
        if (t < st) red[t] += red[t + st];
        __syncthreads();
    }
    if (t < 16) orow[b * DIM + fg * 16 + t] = red[t];
}

// ---- K5: out[b,q,:] = orow[b,:] for all q (16.8 MB NT write) ----
__global__ __launch_bounds__(256) void k5_bcast(const float4* __restrict__ orow4,
                                                float4* __restrict__ out) {
    const int blk = blockIdx.x, t = threadIdx.x;
    const int b = blk >> 8, qg = blk & 255;
    const int rg = t >> 7, f4 = t & 127;
    const f32x4 val = reinterpret_cast<const f32x4*>(orow4)[b * (DIM / 4) + f4];
    f32x4* dst = reinterpret_cast<f32x4*>(out)
               + (size_t)(b * QLEN + qg * RPC) * (DIM / 4);
#pragma unroll
    for (int i = 0; i < 4; ++i)
        __builtin_nontemporal_store(val, &dst[(size_t)(rg + 2 * i) * (DIM / 4) + f4]);
}

extern "C" void kernel_launch(void* const* d_in, const int* in_sizes, int n_in,
                              void* d_out, int out_size, void* d_ws, size_t ws_size,
                              hipStream_t stream) {
    // inputs: 0=query (unused), 1=context, 2=mask (unused), 3=Wq (unused), 4=Wkv, 5=Wout
    const float* ctx  = (const float*)d_in[1];
    const float* Wkv  = (const float*)d_in[4];
    const float* Wout = (const float*)d_in[5];
    float* ws = (float*)d_ws;
    float* partial = ws;                                   // NBLK1*DIM = 524288 f
    float* csum    = partial + (size_t)NBLK1 * DIM;        // BATCH*DIM = 2048 f
    float* vsum    = csum + BATCH * DIM;                   // BATCH*DIM
    float* orow    = vsum + BATCH * DIM;                   // BATCH*DIM

    k1_partial<<<NBLK1, 256, 0, stream>>>(ctx, (float4*)partial);
    k2_reduce<<<512, 256, 0, stream>>>((const float4*)partial, (float4*)csum);
    k3_vsum<<<128, 256, 0, stream>>>(csum, Wkv, vsum);
    k4_orow<<<128, 256, 0, stream>>>(vsum, Wout, orow);
    k5_bcast<<<NBLK1, 256, 0, stream>>>((const float4*)orow, (float4*)d_out);
}